// Round 14
// baseline (416.134 us; speedup 1.0000x reference)
//
#include <hip/hip_runtime.h>
#include <hip/hip_bf16.h>

// Classifier_69818988363910:
//   F = mean_pool_J30(relu(x @ W1^T))                [2000, 2048]
//   logits = F @ (Wlin[:, :2048]+Wlin[:, 2048:])^T   [2000, 1000]
// (y, W2 are dead per the reference's own bug; features2 == features)

typedef __attribute__((ext_vector_type(4))) float f32x4;
typedef __attribute__((ext_vector_type(8))) short short8;

__device__ __forceinline__ unsigned short f2bf(float f) {
  unsigned int u = __float_as_uint(f);
  unsigned int r = (u + 0x7fffu + ((u >> 16) & 1u)) >> 16;
  return (unsigned short)r;
}

__device__ __forceinline__ unsigned long long pack4(f32x4 v) {
  return (unsigned long long)f2bf(v.x)
       | ((unsigned long long)f2bf(v.y) << 16)
       | ((unsigned long long)f2bf(v.z) << 32)
       | ((unsigned long long)f2bf(v.w) << 48);
}

__device__ __forceinline__ void gload_lds16(const unsigned short* gp, unsigned short* lp) {
  __builtin_amdgcn_global_load_lds((const __attribute__((address_space(1))) void*)gp,
                                   (__attribute__((address_space(3))) void*)lp, 16, 0, 0);
}

__global__ void cvt_f32_bf16(const float* __restrict__ src,
                             unsigned short* __restrict__ dst, int n4) {
  int i = blockIdx.x * 256 + threadIdx.x;
  if (i >= n4) return;
  f32x4 v = *(const f32x4*)(src + (size_t)i * 4);
  *(unsigned long long*)(dst + (size_t)i * 4) = pack4(v);
}

__global__ void prep_wsum(const float* __restrict__ wlin,
                          unsigned short* __restrict__ dst) {
  int i = blockIdx.x * 256 + threadIdx.x;
  if (i >= 1000 * 512) return;
  int c = i >> 9, f4 = i & 511;
  const float* p0 = wlin + (size_t)c * 4096 + f4 * 4;
  f32x4 a = *(const f32x4*)p0;
  f32x4 b = *(const f32x4*)(p0 + 2048);
  f32x4 s = a + b;
  *(unsigned long long*)(dst + (size_t)c * 2048 + f4 * 4) = pack4(s);
}

// ---------------------------------------------------------------------------
// GEMM1 occupancy restructure: 128x128 tile, 256 threads = 4 waves (2x2 of
// 64x64), acc 64 AGPR + ~55 arch VGPR -> 3 waves/SIMD -> 3 BLOCKS/CU
// (LDS 48KB x 3 = 144KB <= 160). R3-R13 proved the 256-tile 1-block/CU
// variants all serialize the LDS-read and MFMA pipes (time = pipe SUM,
// MfmaUtil stuck at 43%); 3 independent blocks at unaligned barrier phases
// overlap the pipes (m114 mechanism).
// Ring: 3 slots x (A[128][32] + B[128][32]) bf16; one barrier per K-32 tile;
// stage(t+2) under compute(t) into slot (t-1)%3 (retired one barrier ago);
// counted WAITV(4) (drain-before-barrier, per-wave vmcnt semantics - R8).
// Swizzle: R10-measured-good chunk ^= (row>>1)&3, pre-swizzled global k.
// ---------------------------------------------------------------------------
#define WAITV(n) asm volatile("s_waitcnt vmcnt(" #n ")" ::: "memory")
#define CFENCE() asm volatile("" ::: "memory")

__global__ __launch_bounds__(256, 3)
void gemm128_pool(const unsigned short* __restrict__ A,
                  const unsigned short* __restrict__ B,
                  unsigned short* __restrict__ feat,
                  int Mv, int K) {
  __shared__ __align__(16) unsigned short smem[24576];  // 48 KB

  const int tid = threadIdx.x;
  const int lane = tid & 63;
  const int w = tid >> 6;          // 0..3
  const int wr = w >> 1;           // 0..1  (M half, 64 rows)
  const int wc = w & 1;            // 0..1  (N half, 64 cols)

  // XCD-chunked bijective swizzle: 8000 blocks, 8 XCDs, 1000 each.
  // Within a chunk, 16 consecutive blocks share one A-panel (L2 reuse);
  // B (4 MB bf16) fits the per-XCD L2.
  const int bid = blockIdx.x;
  const int swz = (bid & 7) * 1000 + (bid >> 3);
  const int by = swz >> 4;         // 0..499  M-block (120 valid rows)
  const int bx = swz & 15;         // 0..15   N-block (128 cols)
  const int bm0 = by * 120;
  const int bn0 = bx * 128;
  const int NT = K >> 5;           // K-tiles of 32 (=32)

  // staging: 4 loads/thread/tile (A rows 0-63,64-127; B rows 0-63,64-127).
  // lane covers row h*64 + w*16 + (lane>>2), phys chunk lane&3; pre-swizzled
  // logical k-chunk = (lane&3) ^ ((row>>1)&3) = (lane&3) ^ ((lane>>3)&3).
  const int kslot = (((lane & 3) ^ ((lane >> 3) & 3)) * 8);
  int rA0 = bm0 + 0  + w * 16 + (lane >> 2); if (rA0 >= Mv) rA0 = Mv - 1;
  int rA1 = bm0 + 64 + w * 16 + (lane >> 2); if (rA1 >= Mv) rA1 = Mv - 1;
  const int rB0 = bn0 + 0  + w * 16 + (lane >> 2);
  const int rB1 = bn0 + 64 + w * 16 + (lane >> 2);
  const unsigned short* gA0 = A + (size_t)rA0 * K + kslot;
  const unsigned short* gA1 = A + (size_t)rA1 * K + kslot;
  const unsigned short* gB0 = B + (size_t)rB0 * K + kslot;
  const unsigned short* gB1 = B + (size_t)rB1 * K + kslot;

// slot s (s=t%3): A[128][32] at s*8192 shorts, B[128][32] at s*8192+4096
#define STAGE(tt) do {                                                   \
    const size_t _ko = (size_t)(tt) * 32;                                \
    const int _sb = ((tt) % 3) * 8192;                                   \
    gload_lds16(gA0 + _ko, smem + _sb +    0 + w * 512);                 \
    gload_lds16(gA1 + _ko, smem + _sb + 2048 + w * 512);                 \
    gload_lds16(gB0 + _ko, smem + _sb + 4096 + w * 512);                 \
    gload_lds16(gB1 + _ko, smem + _sb + 6144 + w * 512);                 \
  } while (0)

  f32x4 acc[4][4];
#pragma unroll
  for (int i = 0; i < 4; ++i)
#pragma unroll
    for (int j = 0; j < 4; ++j) acc[i][j] = (f32x4){0.f, 0.f, 0.f, 0.f};

  // fragment reads: row R (stride 32 shorts), phys chunk = q ^ ((fr>>1)&3)
  const int fr = lane & 15;
  const int qa8 = (((lane >> 4) ^ ((fr >> 1) & 3)) * 8);

  STAGE(0); STAGE(1);

  for (int t = 0; t < NT; ++t) {
    if (t < NT - 1) { WAITV(4); } else { WAITV(0); }
    CFENCE();
    __builtin_amdgcn_s_barrier();
    CFENCE();
    if (t + 2 < NT) STAGE(t + 2);   // slot (t-1)%3 — retired last barrier

    const int sb = (t % 3) * 8192;
    short8 afr[4], bfr[4];
#pragma unroll
    for (int j = 0; j < 4; ++j)
      bfr[j] = *(const short8*)(smem + sb + 4096 +
                                (wc * 64 + j * 16 + fr) * 32 + qa8);
#pragma unroll
    for (int i = 0; i < 4; ++i)
      afr[i] = *(const short8*)(smem + sb +
                                (wr * 64 + i * 16 + fr) * 32 + qa8);

    __builtin_amdgcn_s_setprio(1);
#pragma unroll
    for (int i = 0; i < 4; ++i)
#pragma unroll
      for (int j = 0; j < 4; ++j)
        acc[i][j] = __builtin_amdgcn_mfma_f32_16x16x32_bf16(
            afr[i], bfr[j], acc[i][j], 0, 0, 0);
    __builtin_amdgcn_s_setprio(0);
    CFENCE();
  }

  WAITV(0);                         // drain tail stages before panel reuse
  CFENCE();
  __builtin_amdgcn_s_barrier();

  // ---- epilogue: relu + J=30 mean pool via padded f32 [128][65] panel ----
  float* panel = (float*)smem;      // 33280 B <= 48 KB
  const int q4 = (lane >> 4) * 4;
#pragma unroll 1
  for (int c = 0; c < 2; ++c) {
    if (wc == c) {
#pragma unroll
      for (int i = 0; i < 4; ++i)
#pragma unroll
        for (int j = 0; j < 4; ++j)
#pragma unroll
          for (int r = 0; r < 4; ++r)
            panel[(wr * 64 + i * 16 + q4 + r) * 65 + j * 16 + fr] =
                fmaxf(acc[i][j][r], 0.f);
    }
    __builtin_amdgcn_s_barrier();
    CFENCE();
    {
      int col = tid & 63;
      int s = tid >> 6;             // 0..3 segments (rows 0..119)
      float sum = 0.f;
#pragma unroll
      for (int r = 0; r < 30; ++r) sum += panel[(s * 30 + r) * 65 + col];
      int gseg = by * 4 + s;
      int gcol = bn0 + c * 64 + col;
      feat[(size_t)gseg * 2048 + gcol] = f2bf(sum * (1.f / 30.f));
    }
    CFENCE();
    __builtin_amdgcn_s_barrier();
  }
#undef STAGE
}

// ---------------------------------------------------------------------------
// 128x128 kernel: GEMM2 (MODE 2) and the no-workspace fallback (MODE 0).
// ---------------------------------------------------------------------------
#define BM 128
#define BN 128
#define BK 64

template<int MODE>
__global__ __launch_bounds__(256, 2)
void gemm_bt(const void* __restrict__ Ap, const void* __restrict__ Bp,
             void* __restrict__ Cp, int Mv, int Nv, int K, int mstep) {
  constexpr int LDK = (MODE == 0) ? 72 : 64;
  __shared__ __align__(16) unsigned short smem[2 * BM * LDK];
  unsigned short* As = smem;
  unsigned short* Bs = smem + BM * LDK;
  float* Cs = (float*)smem;

  const int tid = threadIdx.x;
  const int lane = tid & 63;
  const int w = tid >> 6;
  const int wr = w >> 1, wc = w & 1;
  const int bm0 = blockIdx.y * mstep;
  const int bn0 = blockIdx.x * BN;

  f32x4 acc[4][4];
#pragma unroll
  for (int i = 0; i < 4; ++i)
#pragma unroll
    for (int j = 0; j < 4; ++j) acc[i][j] = (f32x4){0.f, 0.f, 0.f, 0.f};

  const int fr = lane & 15;
  const int ko = (lane >> 4) * 8;

  for (int kt = 0; kt < K; kt += BK) {
    __syncthreads();
    if constexpr (MODE == 0) {
      const float* A = (const float*)Ap;
      const float* B = (const float*)Bp;
      const int r0 = tid >> 4, kq = tid & 15;
#pragma unroll
      for (int i = 0; i < 8; ++i) {
        int row = i * 16 + r0;
        {
          int gm = bm0 + row;
          f32x4 v = {0.f, 0.f, 0.f, 0.f};
          if (gm < Mv) v = *(const f32x4*)(A + (size_t)gm * K + kt + kq * 4);
          *(unsigned long long*)(As + row * LDK + kq * 4) = pack4(v);
        }
        {
          int gn = bn0 + row;
          f32x4 v = {0.f, 0.f, 0.f, 0.f};
          if (gn < Nv) v = *(const f32x4*)(B + (size_t)gn * K + kt + kq * 4);
          *(unsigned long long*)(Bs + row * LDK + kq * 4) = pack4(v);
        }
      }
    } else {
      const unsigned short* A = (const unsigned short*)Ap;
      const unsigned short* B = (const unsigned short*)Bp;
      const int rsub = lane >> 3;
      const int k8 = (((lane & 7) ^ (lane >> 3)) * 8);
#pragma unroll
      for (int j = 0; j < 4; ++j) {
        int g = w * 4 + j;
        int row = g * 8 + rsub;
        int gm = bm0 + row; if (gm >= Mv) gm = Mv - 1;
        gload_lds16(A + (size_t)gm * K + kt + k8, As + g * 512);
        int gn = bn0 + row; if (gn >= Nv) gn = Nv - 1;
        gload_lds16(B + (size_t)gn * K + kt + k8, Bs + g * 512);
      }
    }
    __syncthreads();
#pragma unroll
    for (int kk = 0; kk < 2; ++kk) {
      const int coffA = (MODE == 0) ? (kk * 32 + ko)
                                    : ((((kk << 2) | (lane >> 4)) ^ (fr & 7)) * 8);
      short8 af[4], bfr[4];
#pragma unroll
      for (int i = 0; i < 4; ++i)
        af[i] = *(const short8*)(As + (wr * 64 + i * 16 + fr) * LDK + coffA);
#pragma unroll
      for (int i = 0; i < 4; ++i)
        bfr[i] = *(const short8*)(Bs + (wc * 64 + i * 16 + fr) * LDK + coffA);
#pragma unroll
      for (int i = 0; i < 4; ++i)
#pragma unroll
        for (int j = 0; j < 4; ++j)
          acc[i][j] = __builtin_amdgcn_mfma_f32_16x16x32_bf16(af[i], bfr[j], acc[i][j], 0, 0, 0);
    }
  }
  __syncthreads();

  if constexpr (MODE != 2) {
    unsigned short* feat = (unsigned short*)Cp;
    const int cr0 = (lane >> 4) * 4;
#pragma unroll
    for (int half = 0; half < 2; ++half) {
      if (wc == half) {
#pragma unroll
        for (int i = 0; i < 4; ++i)
#pragma unroll
          for (int j = 0; j < 4; ++j)
#pragma unroll
            for (int r = 0; r < 4; ++r)
              Cs[(wr * 64 + i * 16 + cr0 + r) * 64 + j * 16 + fr] =
                  fmaxf(acc[i][j][r], 0.f);
      }
      __syncthreads();
      {
        int col = tid & 63;
        int s = tid >> 6;
        float sum = 0.f;
#pragma unroll
        for (int r = 0; r < 30; ++r) sum += Cs[(s * 30 + r) * 64 + col];
        int gseg = blockIdx.y * 4 + s;
        int gcol = bn0 + half * 64 + col;
        feat[(size_t)gseg * 2048 + gcol] = f2bf(sum * (1.f / 30.f));
      }
      __syncthreads();
    }
  } else {
    float* out = (float*)Cp;
    const int cr0 = (lane >> 4) * 4;
#pragma unroll
    for (int i = 0; i < 4; ++i)
#pragma unroll
      for (int j = 0; j < 4; ++j)
#pragma unroll
        for (int r = 0; r < 4; ++r) {
          int gm = bm0 + wr * 64 + i * 16 + cr0 + r;
          int gn = bn0 + wc * 64 + j * 16 + fr;
          if (gm < Mv && gn < Nv) out[(size_t)gm * Nv + gn] = acc[i][j][r];
        }
  }
}

extern "C" void kernel_launch(void* const* d_in, const int* in_sizes, int n_in,
                              void* d_out, int out_size, void* d_ws, size_t ws_size,
                              hipStream_t stream) {
  const float* x    = (const float*)d_in[0];
  const float* W1   = (const float*)d_in[2];
  const float* Wlin = (const float*)d_in[4];
  float* out = (float*)d_out;

  const int T = 60000, DIN = 1024, E = 2048, C = 1000, S = 2000;
  char* ws = (char*)d_ws;
  const size_t off_feat = 0;
  const size_t off_wsum = (size_t)S * E * 2;
  const size_t off_w1b  = off_wsum + (size_t)C * E * 2;
  const size_t off_xb   = off_w1b + (size_t)E * DIN * 2;
  const size_t need_full = off_xb + (size_t)T * DIN * 2;   // ~139.4 MB

  unsigned short* feat = (unsigned short*)(ws + off_feat);
  unsigned short* wsum = (unsigned short*)(ws + off_wsum);

  prep_wsum<<<dim3((C * E / 4 + 255) / 256), dim3(256), 0, stream>>>(Wlin, wsum);

  if (ws_size >= need_full) {
    unsigned short* w1b = (unsigned short*)(ws + off_w1b);
    unsigned short* xb  = (unsigned short*)(ws + off_xb);
    int nx4 = T * DIN / 4;
    cvt_f32_bf16<<<dim3((nx4 + 255) / 256), dim3(256), 0, stream>>>(x, xb, nx4);
    int nw4 = E * DIN / 4;
    cvt_f32_bf16<<<dim3((nw4 + 255) / 256), dim3(256), 0, stream>>>(W1, w1b, nw4);
    // 500 M-blocks (120 rows = 4 segments) x 16 N-blocks (128 cols)
    gemm128_pool<<<dim3(8000), dim3(256), 0, stream>>>(xb, w1b, feat, T, DIN);
  } else {
    gemm_bt<0><<<dim3(16, 500), dim3(256), 0, stream>>>(x, W1, feat, T, E, DIN, 120);
  }

  gemm_bt<2><<<dim3(8, 16), dim3(256), 0, stream>>>(feat, wsum, out, S, C, E, 128);
}

// Round 15
// 374.696 us; speedup vs baseline: 1.1106x; 1.1106x over previous
//
#include <hip/hip_runtime.h>
#include <hip/hip_bf16.h>

// Classifier_69818988363910:
//   F = mean_pool_J30(relu(x @ W1^T))                [2000, 2048]
//   logits = F @ (Wlin[:, :2048]+Wlin[:, 2048:])^T   [2000, 1000]
// (y, W2 are dead per the reference's own bug; features2 == features)

typedef __attribute__((ext_vector_type(4))) float f32x4;
typedef __attribute__((ext_vector_type(8))) short short8;

__device__ __forceinline__ unsigned short f2bf(float f) {
  unsigned int u = __float_as_uint(f);
  unsigned int r = (u + 0x7fffu + ((u >> 16) & 1u)) >> 16;
  return (unsigned short)r;
}

__device__ __forceinline__ unsigned long long pack4(f32x4 v) {
  return (unsigned long long)f2bf(v.x)
       | ((unsigned long long)f2bf(v.y) << 16)
       | ((unsigned long long)f2bf(v.z) << 32)
       | ((unsigned long long)f2bf(v.w) << 48);
}

__device__ __forceinline__ void gload_lds16(const unsigned short* gp, unsigned short* lp) {
  __builtin_amdgcn_global_load_lds((const __attribute__((address_space(1))) void*)gp,
                                   (__attribute__((address_space(3))) void*)lp, 16, 0, 0);
}

__global__ void cvt_f32_bf16(const float* __restrict__ src,
                             unsigned short* __restrict__ dst, int n4) {
  int i = blockIdx.x * 256 + threadIdx.x;
  if (i >= n4) return;
  f32x4 v = *(const f32x4*)(src + (size_t)i * 4);
  *(unsigned long long*)(dst + (size_t)i * 4) = pack4(v);
}

__global__ void prep_wsum(const float* __restrict__ wlin,
                          unsigned short* __restrict__ dst) {
  int i = blockIdx.x * 256 + threadIdx.x;
  if (i >= 1000 * 512) return;
  int c = i >> 9, f4 = i & 511;
  const float* p0 = wlin + (size_t)c * 4096 + f4 * 4;
  f32x4 a = *(const f32x4*)p0;
  f32x4 b = *(const f32x4*)(p0 + 2048);
  f32x4 s = a + b;
  *(unsigned long long*)(dst + (size_t)c * 2048 + f4 * 4) = pack4(s);
}

// ---------------------------------------------------------------------------
// GEMM1: 8-phase schedule, 256x256 tile, BK=64 as 2 K-halves of 32, 2 dbuf
// slot-pairs per matrix (128 KB), counted-vmcnt (R8 ledger), R3-form swizzle
// (R10: conflicts 2.87e7 -> 4.1e6), single trailing barrier per phase (R11).
// R15: FINE INTERLEAVE inside the phase (m196's isolated lever): instead of
// {12 ds_read burst -> 16 MFMA}, order {STAGE, bfr+afr0 reads, 4-MFMA,
// afr1 read, 4-MFMA, afr2 read, 4-MFMA, afr3 read, 4-MFMA}. Each cluster's
// compiler-emitted lgkmcnt covers only its own fragments; later reads issue
// under MFMA execution. Memory-op order across barriers is IDENTICAL to R11
// (same ledger, same hazard proof) — pure intra-phase reorder.
// ---------------------------------------------------------------------------
#define WAITV(n) asm volatile("s_waitcnt vmcnt(" #n ")" ::: "memory")
#define CFENCE() asm volatile("" ::: "memory")

__global__ __launch_bounds__(512, 2)
void gemm256_pool(const unsigned short* __restrict__ A,
                  const unsigned short* __restrict__ B,
                  unsigned short* __restrict__ feat,
                  int Mv, int K) {
  __shared__ __align__(16) unsigned short smem[65536];  // 128 KB

  const int tid = threadIdx.x;
  const int lane = tid & 63;
  const int w = tid >> 6;          // 0..7
  const int wr = w >> 2;           // 0..1  (M half)
  const int wc = w & 3;            // 0..3  (N quarter)

  // XCD-chunked bijective swizzle: 2000 blocks, 8 XCDs, 250 each.
  const int bid = blockIdx.x;
  const int swz = (bid & 7) * 250 + (bid >> 3);
  const int by = swz >> 3;         // 0..249  M-block
  const int bx = swz & 7;          // 0..7    N-block
  const int bm0 = by * 240;
  const int bn0 = bx * 256;
  const int NT2 = K >> 6;          // K-steps of 64 (=16)
  const int NI = NT2 >> 1;         // iterations (=8)

  // staging: lane covers row base+(lane>>2), phys chunk lane&3.
  // logical k-chunk = (lane&3) ^ ((row>>1)&3) = (lane&3) ^ ((lane>>3)&3).
  const int kslot = (((lane & 3) ^ ((lane >> 3) & 3)) * 8);
  int rA0 = bm0 + w * 32 + 0 + (lane >> 2);  if (rA0 >= Mv) rA0 = Mv - 1;
  int rA1 = bm0 + w * 32 + 16 + (lane >> 2); if (rA1 >= Mv) rA1 = Mv - 1;
  const int rB0 = bn0 + w * 32 + 0 + (lane >> 2);
  const int rB1 = bn0 + w * 32 + 16 + (lane >> 2);
  const unsigned short* gA0 = A + (size_t)rA0 * K + kslot;
  const unsigned short* gA1 = A + (size_t)rA1 * K + kslot;
  const unsigned short* gB0 = B + (size_t)rB0 * K + kslot;
  const unsigned short* gB1 = B + (size_t)rB1 * K + kslot;

// slots: A half (S,KS) at ((S)*2+(KS))*8192 shorts; B at +32768
#define STAGE_A(tt, S, KS) do {                                          \
    const size_t _ko = (size_t)(((tt) < NT2) ? (tt) : (NT2 - 1)) * 64 +  \
                       (KS) * 32;                                        \
    gload_lds16(gA0 + _ko, smem + ((S)*2+(KS))*8192 + w * 1024);         \
    gload_lds16(gA1 + _ko, smem + ((S)*2+(KS))*8192 + w * 1024 + 512);   \
  } while (0)
#define STAGE_B(tt, S, KS) do {                                          \
    const size_t _ko = (size_t)(((tt) < NT2) ? (tt) : (NT2 - 1)) * 64 +  \
                       (KS) * 32;                                        \
    gload_lds16(gB0 + _ko, smem + 32768 + ((S)*2+(KS))*8192 + w * 1024); \
    gload_lds16(gB1 + _ko, smem + 32768 + ((S)*2+(KS))*8192 + w * 1024 + 512); \
  } while (0)

  f32x4 acc[8][4];
#pragma unroll
  for (int i = 0; i < 8; ++i)
#pragma unroll
    for (int j = 0; j < 4; ++j) acc[i][j] = (f32x4){0.f, 0.f, 0.f, 0.f};

  // fragment reads: row R (stride 32 shorts), phys chunk = q ^ ((fr>>1)&3)
  const int fr = lane & 15;
  const int qa8 = (((lane >> 4) ^ ((fr >> 1) & 3)) * 8);
#define LDA(S, KS, I) (*(const short8*)(smem + ((S)*2+(KS))*8192 +       \
    (wr * 128 + (I) * 16 + fr) * 32 + qa8))
#define LDB(S, KS, J) (*(const short8*)(smem + 32768 + ((S)*2+(KS))*8192 + \
    (wc * 64 + (J) * 16 + fr) * 32 + qa8))

  short8 bfr[4];

#define CLUSTER(ROW, AF)                                                  \
    _Pragma("unroll") for (int jj = 0; jj < 4; ++jj)                      \
      acc[ROW][jj] = __builtin_amdgcn_mfma_f32_16x16x32_bf16(             \
          AF, bfr[jj], acc[ROW][jj], 0, 0, 0)

  // PHASE (R15): stage first; fine read/MFMA interleave; trailing counted
  // vmcnt + single barrier. Cross-barrier memory-op order == R11.
#define PHASE(S, KS, IH, DOB, TRAILVM, STG) do {                         \
    STG;                                                                 \
    short8 afr0, afr1, afr2, afr3;                                       \
    if (DOB) {                                                           \
      _Pragma("unroll") for (int jj = 0; jj < 4; ++jj)                   \
        bfr[jj] = LDB(S, KS, jj);                                        \
    }                                                                    \
    afr0 = LDA(S, KS, (IH) * 4 + 0);                                     \
    __builtin_amdgcn_s_setprio(1);                                       \
    afr1 = LDA(S, KS, (IH) * 4 + 1);                                     \
    CLUSTER((IH)*4+0, afr0);                                             \
    afr2 = LDA(S, KS, (IH) * 4 + 2);                                     \
    CLUSTER((IH)*4+1, afr1);                                             \
    afr3 = LDA(S, KS, (IH) * 4 + 3);                                     \
    CLUSTER((IH)*4+2, afr2);                                             \
    CLUSTER((IH)*4+3, afr3);                                             \
    __builtin_amdgcn_s_setprio(0);                                       \
    CFENCE();                                                            \
    if (TRAILVM) { WAITV(10); }                                          \
    CFENCE();                                                            \
    __builtin_amdgcn_s_barrier();                                        \
  } while (0)

  // ---- prologue: 7 half-tiles (14 loads/thread), FIFO order matters ----
  STAGE_B(0, 0, 0); STAGE_A(0, 0, 0); STAGE_B(0, 0, 1); STAGE_A(0, 0, 1);
  STAGE_B(1, 1, 0); STAGE_A(1, 1, 0); STAGE_B(1, 1, 1);
  WAITV(10);                        // drain B(0,0), A(0,0)
  CFENCE();
  __builtin_amdgcn_s_barrier();     // all waves drained -> p0 reads are safe

  for (int j = 0; j < NI; ++j) {
    const int t0 = 2 * j, t1 = 2 * j + 1;
    PHASE(0, 0, 0, 1, 0, STAGE_A(t1,     1, 1));  // p0
    PHASE(0, 0, 1, 0, 1, STAGE_B(t0 + 2, 0, 0));  // p1 (drain for p2)
    PHASE(0, 1, 0, 1, 0, STAGE_A(t0 + 2, 0, 0));  // p2
    PHASE(0, 1, 1, 0, 1, STAGE_B(t0 + 2, 0, 1));  // p3 (drain for p4)
    PHASE(1, 0, 0, 1, 0, STAGE_A(t0 + 2, 0, 1));  // p4
    PHASE(1, 0, 1, 0, 1, STAGE_B(t1 + 2, 1, 0));  // p5 (drain for p6)
    PHASE(1, 1, 0, 1, 0, STAGE_A(t1 + 2, 1, 0));  // p6
    PHASE(1, 1, 1, 0, 1, STAGE_B(t1 + 2, 1, 1));  // p7 (drain for next p0)
  }

  // drain pending (clamped) tail stages before panel reuse
  WAITV(0);
  CFENCE();
  __builtin_amdgcn_s_barrier();

  // ---- epilogue: relu + J=30 mean pool via padded f32 [256][65] panel ----
  float* panel = (float*)smem;      // 66560 B <= 128 KB
  const int q4 = (lane >> 4) * 4;
#pragma unroll 1
  for (int c = 0; c < 4; ++c) {
    if (wc == c) {
#pragma unroll
      for (int i = 0; i < 8; ++i)
#pragma unroll
        for (int jj = 0; jj < 4; ++jj)
#pragma unroll
          for (int r = 0; r < 4; ++r)
            panel[(wr * 128 + i * 16 + q4 + r) * 65 + jj * 16 + fr] =
                fmaxf(acc[i][jj][r], 0.f);
    }
    __builtin_amdgcn_s_barrier();
    CFENCE();
    {
      int col = tid & 63;
      int s = tid >> 6;
      float sum = 0.f;
#pragma unroll
      for (int r = 0; r < 30; ++r) sum += panel[(s * 30 + r) * 65 + col];
      int gseg = by * 8 + s;
      int gcol = bn0 + c * 64 + col;
      feat[(size_t)gseg * 2048 + gcol] = f2bf(sum * (1.f / 30.f));
    }
    CFENCE();
    __builtin_amdgcn_s_barrier();
  }
#undef PHASE
#undef CLUSTER
#undef LDA
#undef LDB
#undef STAGE_A
#undef STAGE_B
}

// ---------------------------------------------------------------------------
// 128x128 kernel: GEMM2 (MODE 2) and the no-workspace fallback (MODE 0).
// ---------------------------------------------------------------------------
#define BM 128
#define BN 128
#define BK 64

template<int MODE>
__global__ __launch_bounds__(256, 2)
void gemm_bt(const void* __restrict__ Ap, const void* __restrict__ Bp,
             void* __restrict__ Cp, int Mv, int Nv, int K, int mstep) {
  constexpr int LDK = (MODE == 0) ? 72 : 64;
  __shared__ __align__(16) unsigned short smem[2 * BM * LDK];
  unsigned short* As = smem;
  unsigned short* Bs = smem + BM * LDK;
  float* Cs = (float*)smem;

  const int tid = threadIdx.x;
  const int lane = tid & 63;
  const int w = tid >> 6;
  const int wr = w >> 1, wc = w & 1;
  const int bm0 = blockIdx.y * mstep;
  const int bn0 = blockIdx.x * BN;

  f32x4 acc[4][4];
#pragma unroll
  for (int i = 0; i < 4; ++i)
#pragma unroll
    for (int j = 0; j < 4; ++j) acc[i][j] = (f32x4){0.f, 0.f, 0.f, 0.f};

  const int fr = lane & 15;
  const int ko = (lane >> 4) * 8;

  for (int kt = 0; kt < K; kt += BK) {
    __syncthreads();
    if constexpr (MODE == 0) {
      const float* A = (const float*)Ap;
      const float* B = (const float*)Bp;
      const int r0 = tid >> 4, kq = tid & 15;
#pragma unroll
      for (int i = 0; i < 8; ++i) {
        int row = i * 16 + r0;
        {
          int gm = bm0 + row;
          f32x4 v = {0.f, 0.f, 0.f, 0.f};
          if (gm < Mv) v = *(const f32x4*)(A + (size_t)gm * K + kt + kq * 4);
          *(unsigned long long*)(As + row * LDK + kq * 4) = pack4(v);
        }
        {
          int gn = bn0 + row;
          f32x4 v = {0.f, 0.f, 0.f, 0.f};
          if (gn < Nv) v = *(const f32x4*)(B + (size_t)gn * K + kt + kq * 4);
          *(unsigned long long*)(Bs + row * LDK + kq * 4) = pack4(v);
        }
      }
    } else {
      const unsigned short* A = (const unsigned short*)Ap;
      const unsigned short* B = (const unsigned short*)Bp;
      const int rsub = lane >> 3;
      const int k8 = (((lane & 7) ^ (lane >> 3)) * 8);
#pragma unroll
      for (int j = 0; j < 4; ++j) {
        int g = w * 4 + j;
        int row = g * 8 + rsub;
        int gm = bm0 + row; if (gm >= Mv) gm = Mv - 1;
        gload_lds16(A + (size_t)gm * K + kt + k8, As + g * 512);
        int gn = bn0 + row; if (gn >= Nv) gn = Nv - 1;
        gload_lds16(B + (size_t)gn * K + kt + k8, Bs + g * 512);
      }
    }
    __syncthreads();
#pragma unroll
    for (int kk = 0; kk < 2; ++kk) {
      const int coffA = (MODE == 0) ? (kk * 32 + ko)
                                    : ((((kk << 2) | (lane >> 4)) ^ (fr & 7)) * 8);
      short8 af[4], bfr[4];
#pragma unroll
      for (int i = 0; i < 4; ++i)
        af[i] = *(const short8*)(As + (wr * 64 + i * 16 + fr) * LDK + coffA);
#pragma unroll
      for (int i = 0; i < 4; ++i)
        bfr[i] = *(const short8*)(Bs + (wc * 64 + i * 16 + fr) * LDK + coffA);
#pragma unroll
      for (int i = 0; i < 4; ++i)
#pragma unroll
        for (int j = 0; j < 4; ++j)
          acc[i][j] = __builtin_amdgcn_mfma_f32_16x16x32_bf16(af[i], bfr[j], acc[i][j], 0, 0, 0);
    }
  }
  __syncthreads();

  if constexpr (MODE != 2) {
    unsigned short* feat = (unsigned short*)Cp;
    const int cr0 = (lane >> 4) * 4;
#pragma unroll
    for (int half = 0; half < 2; ++half) {
      if (wc == half) {
#pragma unroll
        for (int i = 0; i < 4; ++i)
#pragma unroll
          for (int j = 0; j < 4; ++j)
#pragma unroll
            for (int r = 0; r < 4; ++r)
              Cs[(wr * 64 + i * 16 + cr0 + r) * 64 + j * 16 + fr] =
                  fmaxf(acc[i][j][r], 0.f);
      }
      __syncthreads();
      {
        int col = tid & 63;
        int s = tid >> 6;
        float sum = 0.f;
#pragma unroll
        for (int r = 0; r < 30; ++r) sum += Cs[(s * 30 + r) * 64 + col];
        int gseg = blockIdx.y * 4 + s;
        int gcol = bn0 + half * 64 + col;
        feat[(size_t)gseg * 2048 + gcol] = f2bf(sum * (1.f / 30.f));
      }
      __syncthreads();
    }
  } else {
    float* out = (float*)Cp;
    const int cr0 = (lane >> 4) * 4;
#pragma unroll
    for (int i = 0; i < 4; ++i)
#pragma unroll
      for (int j = 0; j < 4; ++j)
#pragma unroll
        for (int r = 0; r < 4; ++r) {
          int gm = bm0 + wr * 64 + i * 16 + cr0 + r;
          int gn = bn0 + wc * 64 + j * 16 + fr;
          if (gm < Mv && gn < Nv) out[(size_t)gm * Nv + gn] = acc[i][j][r];
        }
  }
}

extern "C" void kernel_launch(void* const* d_in, const int* in_sizes, int n_in,
                              void* d_out, int out_size, void* d_ws, size_t ws_size,
                              hipStream_t stream) {
  const float* x    = (const float*)d_in[0];
  const float* W1   = (const float*)d_in[2];
  const float* Wlin = (const float*)d_in[4];
  float* out = (float*)d_out;

  const int T = 60000, DIN = 1024, E = 2048, C = 1000, S = 2000;
  char* ws = (char*)d_ws;
  const size_t off_feat = 0;
  const size_t off_wsum = (size_t)S * E * 2;
  const size_t off_w1b  = off_wsum + (size_t)C * E * 2;
  const size_t off_xb   = off_w1b + (size_t)E * DIN * 2;
  const size_t need_full = off_xb + (size_t)T * DIN * 2;   // ~139.4 MB

  unsigned short* feat = (unsigned short*)(ws + off_feat);
  unsigned short* wsum = (unsigned short*)(ws + off_wsum);

  prep_wsum<<<dim3((C * E / 4 + 255) / 256), dim3(256), 0, stream>>>(Wlin, wsum);

  if (ws_size >= need_full) {
    unsigned short* w1b = (unsigned short*)(ws + off_w1b);
    unsigned short* xb  = (unsigned short*)(ws + off_xb);
    int nx4 = T * DIN / 4;
    cvt_f32_bf16<<<dim3((nx4 + 255) / 256), dim3(256), 0, stream>>>(x, xb, nx4);
    int nw4 = E * DIN / 4;
    cvt_f32_bf16<<<dim3((nw4 + 255) / 256), dim3(256), 0, stream>>>(W1, w1b, nw4);
    gemm256_pool<<<dim3(2000), dim3(512), 0, stream>>>(xb, w1b, feat, T, DIN);
  } else {
    gemm_bt<0><<<dim3(16, 500), dim3(256), 0, stream>>>(x, W1, feat, T, E, DIN, 120);
  }

  gemm_bt<2><<<dim3(8, 16), dim3(256), 0, stream>>>(feat, wsum, out, S, C, E, 128);
}